// Round 10
// baseline (604.690 us; speedup 1.0000x reference)
//
#include <hip/hip_runtime.h>

using u16 = unsigned short;
using u32 = unsigned int;

typedef __bf16 bf16x8 __attribute__((ext_vector_type(8)));
typedef float  f32x4  __attribute__((ext_vector_type(4)));
typedef _Float16 f16;
typedef _Float16 f16x4 __attribute__((ext_vector_type(4)));
typedef _Float16 f16x8 __attribute__((ext_vector_type(8)));
typedef u16 u16x4 __attribute__((ext_vector_type(4)));

__device__ __forceinline__ float b2f(u16 u) { return __uint_as_float(((u32)u) << 16); }
__device__ __forceinline__ u16 f2b(float f) {
    u32 u = __float_as_uint(f);
    return (u16)((u + 0x7FFFu + ((u >> 16) & 1u)) >> 16);  // RNE
}

// async global->LDS, 16 B per lane.
__device__ __forceinline__ void async_cp16(void* lds, const void* g) {
    __builtin_amdgcn_global_load_lds(
        (const __attribute__((address_space(1))) u32*)g,
        (__attribute__((address_space(3))) u32*)lds, 16, 0, 0);
}

// fp32x4 -> (hi, lo) bf16 planes (bit-identical to old in-kernel split8)
__device__ __forceinline__ void split4_store(const float* src, u16* hi, u16* lo, int i) {
    f32x4 v = reinterpret_cast<const f32x4*>(src)[i];
    u16x4 H, L;
#pragma unroll
    for (int j = 0; j < 4; j++) {
        u16 hb = f2b(v[j]);
        H[j] = hb;
        L[j] = f2b(v[j] - b2f(hb));
    }
    reinterpret_cast<u16x4*>(hi)[i] = H;
    reinterpret_cast<u16x4*>(lo)[i] = L;
}

// ---------------------------------------------------------------------------
// Fused prep: x->f16; Wq->f16 hi/lo; Wp->f16; y->bf16 hi/lo; Wkv->bf16 hi/lo
// ---------------------------------------------------------------------------
__global__ __launch_bounds__(256) void prep(const float* __restrict__ x,
                                            const float* __restrict__ Wq,
                                            const float* __restrict__ Wp,
                                            const float* __restrict__ y,
                                            const float* __restrict__ Wkv,
                                            f16* __restrict__ xf,
                                            f16* __restrict__ wqhi, f16* __restrict__ wqlo,
                                            f16* __restrict__ wph,
                                            u16* __restrict__ yhi, u16* __restrict__ ylo,
                                            u16* __restrict__ wkhi, u16* __restrict__ wklo,
                                            int nx4, int nw4, int ny4, int nwk4) {
    int i = blockIdx.x * 256 + threadIdx.x;
    if (i < nx4) {
        f32x4 v = reinterpret_cast<const f32x4*>(x)[i];
        f16x4 h = {(f16)v[0], (f16)v[1], (f16)v[2], (f16)v[3]};
        reinterpret_cast<f16x4*>(xf)[i] = h;
    } else if (i < nx4 + nw4) {
        int k = i - nx4;
        f32x4 v = reinterpret_cast<const f32x4*>(Wq)[k];
        f16x4 H, L;
#pragma unroll
        for (int j = 0; j < 4; j++) {
            f16 hb = (f16)v[j];
            H[j] = hb;
            L[j] = (f16)(v[j] - (float)hb);
        }
        reinterpret_cast<f16x4*>(wqhi)[k] = H;
        reinterpret_cast<f16x4*>(wqlo)[k] = L;
    } else if (i < nx4 + 2 * nw4) {
        int k = i - nx4 - nw4;
        f32x4 v = reinterpret_cast<const f32x4*>(Wp)[k];
        f16x4 h = {(f16)v[0], (f16)v[1], (f16)v[2], (f16)v[3]};
        reinterpret_cast<f16x4*>(wph)[k] = h;
    } else if (i < nx4 + 2 * nw4 + ny4) {
        int k = i - nx4 - 2 * nw4;
        split4_store(y, yhi, ylo, k);
    } else {
        int k = i - nx4 - 2 * nw4 - ny4;
        if (k < nwk4) split4_store(Wkv, wkhi, wklo, k);
    }
}

// Bijective XCD-colocating remap for 1704 q-blocks (426 m-tiles x 4 hg).
// Blocks 8 apart share an XCD: the 4 hg blocks of one m-tile land together.
__device__ __forceinline__ void remap1704(int j, int& mt, int& sg) {
    if (j < 1696) {
        int a = j >> 5, rem = j & 31;
        mt = a * 8 + (rem & 7);   // [0,423]
        sg = rem >> 3;            // [0,3]
    } else {
        int rem = j - 1696;       // [0,8)
        mt = 424 + (rem >> 2);    // 424..425
        sg = rem & 3;
    }
}

// freqs for cross RoPE: 10000^(-f/16) = 10^(-f/4)
__constant__ double FREQS16[16] = {
    1.0, 0.5623413251903491, 0.31622776601683794, 0.17782794100389228,
    0.1, 0.05623413251903491, 0.03162277660168379, 0.017782794100389228,
    0.01, 0.005623413251903491, 0.0031622776601683794, 0.0017782794100389228,
    0.001, 0.0005623413251903491, 0.00031622776601683794, 0.00017782794100389228};

// ---------------------------------------------------------------------------
// FUSED q-projection + kv-projection (independent; overlap their latency).
// blockIdx < 288: kv path (round-9 code, pre-split bf16 planes, no LDS).
// blockIdx >= 288: q path, 32-ROW m-tiles (2x blocks vs round-9 -> 2x TLP,
// the only lever that has moved gemm_q). BK=128 staging (16 KB LDS,
// XOR-swizzled, dbl-buffered), W f16 hi/lo direct, 2 MFMA/fragment.
// Per-element accumulation order identical -> bit-identical q and k/v.
// ---------------------------------------------------------------------------
__global__ __launch_bounds__(256) void qkv(const f16* __restrict__ xf,
                                           const f16* __restrict__ whi,
                                           const f16* __restrict__ wlo,
                                           const float* __restrict__ qb,
                                           const float* __restrict__ fc,
                                           const float* __restrict__ smul,
                                           f16* __restrict__ qout,
                                           const u16* __restrict__ yhi,
                                           const u16* __restrict__ ylo,
                                           const u16* __restrict__ wkhi,
                                           const u16* __restrict__ wklo,
                                           const float* __restrict__ vb,
                                           f16* __restrict__ khp,
                                           f16* __restrict__ klp,
                                           f16* __restrict__ vhp,
                                           f16* __restrict__ vlp) {
    const int K = 1024, L = 1704;
    __shared__ f16 xs[2][2][32][64];  // [buf][khalf][row][k] = 16 KB (swizzled)
    int tid = threadIdx.x;
    int lane = tid & 63, wv = tid >> 6;
    int lr = lane & 15, quad = lane >> 4;

    if (blockIdx.x < 288) {
        // ------------------------- KV path -------------------------
        int mt = blockIdx.x >> 3;            // [0,36)
        int nt = (blockIdx.x & 7) * 4 + wv;  // [0,32)
        long m0 = (long)mt * 32;

        const bf16x8* ah_p[2];
        const bf16x8* al_p[2];
        const bf16x8* wh_p[4];
        const bf16x8* wl_p[4];
#pragma unroll
        for (int i = 0; i < 2; i++) {
            long aoff = (m0 + i * 16 + lr) * K;
            ah_p[i] = reinterpret_cast<const bf16x8*>(yhi + aoff) + quad;
            al_p[i] = reinterpret_cast<const bf16x8*>(ylo + aoff) + quad;
        }
#pragma unroll
        for (int i = 0; i < 4; i++) {
            long woff = ((long)(nt * 64 + i * 16 + lr)) * K;
            wh_p[i] = reinterpret_cast<const bf16x8*>(wkhi + woff) + quad;
            wl_p[i] = reinterpret_cast<const bf16x8*>(wklo + woff) + quad;
        }

        f32x4 acc[2][4] = {};
        for (int ks = 0; ks < 32; ks++) {
            int o = ks * 4;
            bf16x8 ah[2], al[2], wh[4], wl[4];
#pragma unroll
            for (int i = 0; i < 2; i++) { ah[i] = ah_p[i][o]; al[i] = al_p[i][o]; }
#pragma unroll
            for (int i = 0; i < 4; i++) { wh[i] = wh_p[i][o]; wl[i] = wl_p[i][o]; }
#pragma unroll
            for (int mi = 0; mi < 2; mi++)
#pragma unroll
                for (int ni = 0; ni < 4; ni++) {
                    acc[mi][ni] = __builtin_amdgcn_mfma_f32_16x16x32_bf16(ah[mi], wh[ni], acc[mi][ni], 0, 0, 0);
                    acc[mi][ni] = __builtin_amdgcn_mfma_f32_16x16x32_bf16(al[mi], wh[ni], acc[mi][ni], 0, 0, 0);
                    acc[mi][ni] = __builtin_amdgcn_mfma_f32_16x16x32_bf16(ah[mi], wl[ni], acc[mi][ni], 0, 0, 0);
                }
        }

        bool isv = nt >= 16;
        int h = isv ? nt - 16 : nt;
#pragma unroll
        for (int mi = 0; mi < 2; mi++) {
#pragma unroll
            for (int r = 0; r < 4; r++) {
                long row = m0 + mi * 16 + quad * 4 + r;  // [0,1152)
                int b = (int)(row / 144), lk = (int)(row % 144);
                long bh = b * 16 + h;
                float v[4];
#pragma unroll
                for (int ni = 0; ni < 4; ni++)
                    v[ni] = acc[mi][ni][r] + (isv ? vb[h * 64 + ni * 16 + lr] : 0.f);
                if (!isv) {
                    float ss = v[0] * v[0] + v[1] * v[1] + v[2] * v[2] + v[3] * v[3];
                    ss += __shfl_xor(ss, 1, 64); ss += __shfl_xor(ss, 2, 64);
                    ss += __shfl_xor(ss, 4, 64); ss += __shfl_xor(ss, 8, 64);
                    float inv = 1.f / fmaxf(sqrtf(ss), 1e-12f);
                    f16* kh_row = khp + (bh * 144 + lk) * 64;
                    f16* kl_row = klp + (bh * 144 + lk) * 64;
#pragma unroll
                    for (int ni = 0; ni < 4; ni++) {
                        float u = v[ni] * inv;
                        int d = ni * 16 + lr;
                        int j = d >> 1;
                        int f = j & 15;
                        float tc = (j < 16) ? ((float)(lk / 12)) / 12.0f * 32.0f
                                            : ((float)(lk % 12)) / 12.0f * 32.0f;
                        float ang = (float)((double)tc * FREQS16[f]);
                        float c = cosf(ang), s = sinf(ang);
                        float pr = __shfl_xor(u, 1, 64);
                        float o = (lane & 1) ? (pr * s + u * c) : (u * c - pr * s);
                        f16 oh = (f16)o;
                        f16 ol = (f16)(o - (float)oh);
                        kh_row[d] = oh;
                        kl_row[d] = ol;
                    }
                } else {
#pragma unroll
                    for (int ni = 0; ni < 4; ni++) {
                        float val = v[ni];
                        int d = ni * 16 + lr;
                        f16 vh = (f16)val;
                        f16 vl = (f16)(val - (float)vh);
                        vhp[(bh * 64 + d) * 144 + lk] = vh;
                        vlp[(bh * 64 + d) * 144 + lk] = vl;
                    }
                }
            }
        }
        return;
    }

    // ------------------------- Q path (32-row tiles) -------------------------
    int mt, hg;
    remap1704(blockIdx.x - 288, mt, hg);
    int h  = hg * 4 + wv;
    long m0 = (long)mt * 32;

    // staging: 256 slots of 16B per half; one slot per thread.
    // slot t -> row t>>3 (0..31), phys col (t&7); global col ((t&7)^(row&7)).
    int r0 = tid >> 3, c0 = tid & 7;
    const f16* srcx0 = xf + (m0 + r0) * K + ((c0 ^ (r0 & 7)) * 8);
    f16* dx[2][2];  // [buf][khalf]
#pragma unroll
    for (int b = 0; b < 2; b++)
#pragma unroll
        for (int hh = 0; hh < 2; hh++) dx[b][hh] = &xs[b][hh][r0][c0 * 8];

    const f16x8* wh_p[4];
    const f16x8* wl_p[4];
#pragma unroll
    for (int i = 0; i < 4; i++) {
        long woff = ((long)(h * 64 + i * 16 + lr)) * K;
        wh_p[i] = reinterpret_cast<const f16x8*>(whi + woff) + quad;
        wl_p[i] = reinterpret_cast<const f16x8*>(wlo + woff) + quad;
    }

    int sp0 = ((0 + quad) ^ (lr & 7)) * 8;
    int sp1 = ((4 + quad) ^ (lr & 7)) * 8;

    f32x4 acc[2][4] = {};

    async_cp16(dx[0][0], srcx0);
    async_cp16(dx[0][1], srcx0 + 64);
    __syncthreads();

    for (int c = 0; c < 8; c++) {
        if (c < 7) {
            int nb = (c + 1) & 1;
            int off = (c + 1) * 128;
            async_cp16(dx[nb][0], srcx0 + off);
            async_cp16(dx[nb][1], srcx0 + off + 64);
        }
        int buf = c & 1;
#pragma unroll
        for (int hh = 0; hh < 2; hh++) {
#pragma unroll
            for (int s = 0; s < 2; s++) {
                int o = (c * 2 + hh) * 8 + s * 4;
                int sp = s ? sp1 : sp0;
                f16x8 AF[2], WH[4], WL[4];
#pragma unroll
                for (int i = 0; i < 4; i++) {
                    WH[i] = wh_p[i][o];
                    WL[i] = wl_p[i][o];
                }
#pragma unroll
                for (int i = 0; i < 2; i++)
                    AF[i] = *reinterpret_cast<const f16x8*>(&xs[buf][hh][i * 16 + lr][sp]);
#pragma unroll
                for (int mi = 0; mi < 2; mi++)
#pragma unroll
                    for (int ni = 0; ni < 4; ni++) {
                        acc[mi][ni] = __builtin_amdgcn_mfma_f32_16x16x32_f16(AF[mi], WH[ni], acc[mi][ni], 0, 0, 0);
                        acc[mi][ni] = __builtin_amdgcn_mfma_f32_16x16x32_f16(AF[mi], WL[ni], acc[mi][ni], 0, 0, 0);
                    }
            }
        }
        __syncthreads();
    }

    float sm = __expf(fminf(smul[h], 4.6051702f));  // ln(100)
#pragma unroll
    for (int mi = 0; mi < 2; mi++) {
#pragma unroll
        for (int r = 0; r < 4; r++) {
            long rowg = m0 + mi * 16 + quad * 4 + r;
            float v[4];
            float ss = 0.f;
#pragma unroll
            for (int ni = 0; ni < 4; ni++) {
                v[ni] = acc[mi][ni][r] + qb[h * 64 + ni * 16 + lr];
                ss += v[ni] * v[ni];
            }
            ss += __shfl_xor(ss, 1, 64); ss += __shfl_xor(ss, 2, 64);
            ss += __shfl_xor(ss, 4, 64); ss += __shfl_xor(ss, 8, 64);
            float inv = sm / fmaxf(sqrtf(ss), 1e-12f);
            int l = (int)(rowg % L);
            f16* orow = qout + rowg * 1024 + h * 64;
#pragma unroll
            for (int ni = 0; ni < 4; ni++) {
                float u = v[ni] * inv;
                int d = ni * 16 + lr;
                int j = d >> 1;
                float c = fc[(l * 32 + j) * 2];
                float s = fc[(l * 32 + j) * 2 + 1];
                float pr = __shfl_xor(u, 1, 64);
                float o = (lane & 1) ? (pr * s + u * c) : (u * c - pr * s);
                orow[d] = (f16)o;
            }
        }
    }
}

// ---------------------------------------------------------------------------
// MFMA attention (unchanged from round-9). Block = 4 independent waves.
// ---------------------------------------------------------------------------
__global__ __launch_bounds__(256, 3) void attn(const f16* q,
                                               const f16* __restrict__ khp,
                                               const f16* __restrict__ klp,
                                               const f16* __restrict__ vhp,
                                               const f16* __restrict__ vlp,
                                               const float* __restrict__ abias,
                                               f16* aout) {
    const int L = 1704;
    __shared__ __align__(16) f16 ps[4][16][152];  // 19.5 KB, per-wave regions
    int tid = threadIdx.x;
    int lane = tid & 63, wv = tid >> 6;
    int lr = lane & 15, quad = lane >> 4;
    int ltile = blockIdx.x % 27;
    int bh = blockIdx.x / 27;  // b*16+h
    int h = bh & 15, b = bh >> 4;
    int l0 = ltile * 64;
    int rows = min(64, L - l0);  // 64 or 40 (tail)

    int rA = wv * 16 + lr;
    int rAc = min(rA, rows - 1);
    const f16* qrow = q + ((long)(b * L + l0 + rAc)) * 1024 + h * 64;
    f16x8 qa0 = *reinterpret_cast<const f16x8*>(qrow + quad * 8);
    f16x8 qa1 = *reinterpret_cast<const f16x8*>(qrow + 32 + quad * 8);

    const f16* khb = khp + (long)bh * (144 * 64);
    const f16* klb = klp + (long)bh * (144 * 64);

    f32x4 acc[9] = {};
#pragma unroll
    for (int t = 0; t < 9; t++) {
        const f16* k0 = khb + (t * 16 + lr) * 64 + quad * 8;
        const f16* k1 = klb + (t * 16 + lr) * 64 + quad * 8;
        f16x8 bh0 = *reinterpret_cast<const f16x8*>(k0);
        f16x8 bh1 = *reinterpret_cast<const f16x8*>(k0 + 32);
        f16x8 bl0 = *reinterpret_cast<const f16x8*>(k1);
        f16x8 bl1 = *reinterpret_cast<const f16x8*>(k1 + 32);
        __builtin_amdgcn_s_setprio(1);
        acc[t] = __builtin_amdgcn_mfma_f32_16x16x32_f16(qa0, bh0, acc[t], 0, 0, 0);
        acc[t] = __builtin_amdgcn_mfma_f32_16x16x32_f16(qa1, bh1, acc[t], 0, 0, 0);
        acc[t] = __builtin_amdgcn_mfma_f32_16x16x32_f16(qa0, bl0, acc[t], 0, 0, 0);
        acc[t] = __builtin_amdgcn_mfma_f32_16x16x32_f16(qa1, bl1, acc[t], 0, 0, 0);
        __builtin_amdgcn_s_setprio(0);
    }

    int rC = wv * 16 + quad * 4;
#pragma unroll
    for (int r = 0; r < 4; r++) {
        long lrow = (long)(l0 + min(rC + r, rows - 1)) * 144;
#pragma unroll
        for (int t = 0; t < 9; t++) acc[t][r] += abias[lrow + t * 16 + lr];
    }

#pragma unroll
    for (int r = 0; r < 4; r++) {
        float mx = acc[0][r];
#pragma unroll
        for (int t = 1; t < 9; t++) mx = fmaxf(mx, acc[t][r]);
        mx = fmaxf(mx, __shfl_xor(mx, 1, 64));
        mx = fmaxf(mx, __shfl_xor(mx, 2, 64));
        mx = fmaxf(mx, __shfl_xor(mx, 4, 64));
        mx = fmaxf(mx, __shfl_xor(mx, 8, 64));
        float s = 0.f;
#pragma unroll
        for (int t = 0; t < 9; t++) {
            float e = __expf(acc[t][r] - mx);
            acc[t][r] = e;
            s += e;
        }
        s += __shfl_xor(s, 1, 64);
        s += __shfl_xor(s, 2, 64);
        s += __shfl_xor(s, 4, 64);
        s += __shfl_xor(s, 8, 64);
        float inv = 1.0f / s;
#pragma unroll
        for (int t = 0; t < 9; t++)
            ps[wv][quad * 4 + r][t * 16 + lr] = (f16)(acc[t][r] * inv);
    }

    const f16* vhb = vhp + (long)bh * (64 * 144);
    const f16* vlb = vlp + (long)bh * (64 * 144);
    f32x4 oacc[4] = {};
#pragma unroll
    for (int ks = 0; ks < 5; ks++) {
        f16x8 pa = {0, 0, 0, 0, 0, 0, 0, 0};
        if (ks < 4 || quad < 2)
            pa = *reinterpret_cast<const f16x8*>(&ps[wv][lr][ks * 32 + quad * 8]);
#pragma unroll
        for (int n = 0; n < 4; n++) {
            f16x8 vh8 = {0, 0, 0, 0, 0, 0, 0, 0};
            f16x8 vl8 = {0, 0, 0, 0, 0, 0, 0, 0};
            if (ks < 4 || quad < 2) {
                const f16* vr  = vhb + (n * 16 + lr) * 144 + ks * 32 + quad * 8;
                const f16* vr2 = vlb + (n * 16 + lr) * 144 + ks * 32 + quad * 8;
                vh8 = *reinterpret_cast<const f16x8*>(vr);
                vl8 = *reinterpret_cast<const f16x8*>(vr2);
            }
            __builtin_amdgcn_s_setprio(1);
            oacc[n] = __builtin_amdgcn_mfma_f32_16x16x32_f16(pa, vh8, oacc[n], 0, 0, 0);
            oacc[n] = __builtin_amdgcn_mfma_f32_16x16x32_f16(pa, vl8, oacc[n], 0, 0, 0);
            __builtin_amdgcn_s_setprio(0);
        }
    }

    long ob = (long)(b * L + l0);
#pragma unroll
    for (int r = 0; r < 4; r++) {
        int rw = rC + r;
        if (rw < rows) {
            f16* ao = aout + (ob + rw) * 1024 + h * 64;
#pragma unroll
            for (int n = 0; n < 4; n++) ao[n * 16 + lr] = (f16)oacc[n][r];
        }
    }
}

// ---------------------------------------------------------------------------
// Final projection, 32-ROW m-tiles (same TLP lever): 1704 blocks via
// remap1704. A f16 staged per BK=128 (16 KB LDS, swizzled, dbl-buffered),
// W f16 per-wave direct. fp32 out.
// ---------------------------------------------------------------------------
__global__ __launch_bounds__(256) void gemm_proj(const f16* __restrict__ A,
                                                 const f16* __restrict__ Wh,
                                                 const float* __restrict__ bias,
                                                 float* __restrict__ out) {
    const int K = 1024;
    __shared__ f16 as[2][2][32][64];  // [buf][khalf][row][k] = 16 KB (swizzled)
    int tid = threadIdx.x;
    int lane = tid & 63, wv = tid >> 6;
    int mt, cg;
    remap1704(blockIdx.x, mt, cg);
    int lr = lane & 15, quad = lane >> 4;
    long m0 = (long)mt * 32;
    long n0 = (long)cg * 256 + wv * 64;

    int r0 = tid >> 3, c0 = tid & 7;
    const f16* srca0 = A + (m0 + r0) * K + ((c0 ^ (r0 & 7)) * 8);
    f16* da[2][2];
#pragma unroll
    for (int b = 0; b < 2; b++)
#pragma unroll
        for (int hh = 0; hh < 2; hh++) da[b][hh] = &as[b][hh][r0][c0 * 8];

    const f16x8* wrow[4];
#pragma unroll
    for (int i = 0; i < 4; i++)
        wrow[i] = reinterpret_cast<const f16x8*>(Wh + (n0 + i * 16 + lr) * K) + quad;

    int sp0 = ((0 + quad) ^ (lr & 7)) * 8;
    int sp1 = ((4 + quad) ^ (lr & 7)) * 8;

    f32x4 acc[2][4] = {};

    async_cp16(da[0][0], srca0);
    async_cp16(da[0][1], srca0 + 64);
    __syncthreads();

    for (int c = 0; c < 8; c++) {
        if (c < 7) {
            int nb = (c + 1) & 1;
            int off = (c + 1) * 128;
            async_cp16(da[nb][0], srca0 + off);
            async_cp16(da[nb][1], srca0 + off + 64);
        }
        int buf = c & 1;
#pragma unroll
        for (int hh = 0; hh < 2; hh++) {
#pragma unroll
            for (int s = 0; s < 2; s++) {
                int o = (c * 2 + hh) * 8 + s * 4;
                int sp = s ? sp1 : sp0;
                f16x8 af[2], wf[4];
#pragma unroll
                for (int i = 0; i < 4; i++) wf[i] = wrow[i][o];
#pragma unroll
                for (int i = 0; i < 2; i++)
                    af[i] = *reinterpret_cast<const f16x8*>(&as[buf][hh][i * 16 + lr][sp]);
#pragma unroll
                for (int mi = 0; mi < 2; mi++)
#pragma unroll
                    for (int ni = 0; ni < 4; ni++)
                        acc[mi][ni] = __builtin_amdgcn_mfma_f32_16x16x32_f16(af[mi], wf[ni], acc[mi][ni], 0, 0, 0);
            }
        }
        __syncthreads();
    }

#pragma unroll
    for (int ni = 0; ni < 4; ni++) {
        int col = (int)n0 + ni * 16 + lr;
        float b = bias[col];
#pragma unroll
        for (int mi = 0; mi < 2; mi++) {
            long row = m0 + mi * 16 + quad * 4;
#pragma unroll
            for (int r = 0; r < 4; r++)
                out[(row + r) * 1024 + col] = acc[mi][ni][r] + b;
        }
    }
}

extern "C" void kernel_launch(void* const* d_in, const int* in_sizes, int n_in,
                              void* d_out, int out_size, void* d_ws, size_t ws_size,
                              hipStream_t stream) {
    const float* x     = (const float*)d_in[0];
    const float* y     = (const float*)d_in[1];
    const float* fc    = (const float*)d_in[2];
    const float* abias = (const float*)d_in[3];
    const float* Wq    = (const float*)d_in[4];
    const float* qb    = (const float*)d_in[5];
    const float* Wkv   = (const float*)d_in[6];
    const float* vb    = (const float*)d_in[7];
    const float* Wp    = (const float*)d_in[8];
    const float* bp    = (const float*)d_in[9];
    const float* smul  = (const float*)d_in[10];

    const long XN  = 13959168L;  // 8*1704*1024
    const long WN  = 1048576L;   // 1024*1024
    const long YN  = 1179648L;   // 8*144*1024
    const long WKN = 2097152L;   // 2048*1024
    const long KVN = 1179648L;   // 128*144*64 (= 128*64*144)

    // d_ws layout (33.9 MB): qbuf fp16 | Wq hi f16 | Wq lo f16 | Wp fp16
    f16* qbuf  = (f16*)d_ws;
    f16* wq_hi = qbuf + XN;
    f16* wq_lo = wq_hi + WN;
    f16* wp_h  = wq_lo + WN;

    // d_out (55.8 MB) phase 1 (50.4 MB used):
    //   x f16 (27.9) | y bf16 hi/lo (4.7) | Wkv bf16 hi/lo (8.4) | K/V planes (9.4)
    // K/V planes placed AFTER Wkv planes: the fused qkv kernel writes them
    // while q-blocks still read x_f (no overlap). All dead before gemm_proj
    // overwrites d_out with the fp32 output.
    f16* x_f   = (f16*)d_out;
    u16* y_hi  = (u16*)(x_f + XN);
    u16* y_lo  = y_hi + YN;
    u16* wk_hi = y_lo + YN;
    u16* wk_lo = wk_hi + WKN;
    f16* kh_p  = (f16*)(wk_lo + WKN);
    f16* kl_p  = kh_p + KVN;
    f16* vth_p = kl_p + KVN;
    f16* vtl_p = vth_p + KVN;

    int nx4  = (int)(XN / 4);
    int nw4  = (int)(WN / 4);
    int ny4  = (int)(YN / 4);
    int nwk4 = (int)(WKN / 4);
    int prep_blocks = (nx4 + 2 * nw4 + ny4 + nwk4 + 255) / 256;

    prep<<<dim3(prep_blocks), dim3(256), 0, stream>>>(
        x, Wq, Wp, y, Wkv, x_f, wq_hi, wq_lo, wp_h,
        y_hi, y_lo, wk_hi, wk_lo, nx4, nw4, ny4, nwk4);
    qkv<<<dim3(288 + 1704), dim3(256), 0, stream>>>(
        x_f, wq_hi, wq_lo, qb, fc, smul, qbuf,
        y_hi, y_lo, wk_hi, wk_lo, vb, kh_p, kl_p, vth_p, vtl_p);
    attn<<<dim3(3456), dim3(256), 0, stream>>>(qbuf, kh_p, kl_p, vth_p, vtl_p, abias, (f16*)qbuf);
    gemm_proj<<<dim3(1704), dim3(256), 0, stream>>>((const f16*)qbuf, wp_h, bp, (float*)d_out);
}

// Round 11
// 539.369 us; speedup vs baseline: 1.1211x; 1.1211x over previous
//
#include <hip/hip_runtime.h>

using u16 = unsigned short;
using u32 = unsigned int;

typedef __bf16 bf16x8 __attribute__((ext_vector_type(8)));
typedef float  f32x4  __attribute__((ext_vector_type(4)));
typedef _Float16 f16;
typedef _Float16 f16x4 __attribute__((ext_vector_type(4)));
typedef _Float16 f16x8 __attribute__((ext_vector_type(8)));
typedef u16 u16x4 __attribute__((ext_vector_type(4)));

__device__ __forceinline__ float b2f(u16 u) { return __uint_as_float(((u32)u) << 16); }
__device__ __forceinline__ u16 f2b(float f) {
    u32 u = __float_as_uint(f);
    return (u16)((u + 0x7FFFu + ((u >> 16) & 1u)) >> 16);  // RNE
}

// async global->LDS, 16 B per lane.
__device__ __forceinline__ void async_cp16(void* lds, const void* g) {
    __builtin_amdgcn_global_load_lds(
        (const __attribute__((address_space(1))) u32*)g,
        (__attribute__((address_space(3))) u32*)lds, 16, 0, 0);
}

// fp32x4 -> (hi, lo) bf16 planes (bit-identical to old in-kernel split8)
__device__ __forceinline__ void split4_store(const float* src, u16* hi, u16* lo, int i) {
    f32x4 v = reinterpret_cast<const f32x4*>(src)[i];
    u16x4 H, L;
#pragma unroll
    for (int j = 0; j < 4; j++) {
        u16 hb = f2b(v[j]);
        H[j] = hb;
        L[j] = f2b(v[j] - b2f(hb));
    }
    reinterpret_cast<u16x4*>(hi)[i] = H;
    reinterpret_cast<u16x4*>(lo)[i] = L;
}

// ---------------------------------------------------------------------------
// Fused prep: x->f16; Wq->f16 hi/lo; Wp->f16; y->bf16 hi/lo; Wkv->bf16 hi/lo
// ---------------------------------------------------------------------------
__global__ __launch_bounds__(256) void prep(const float* __restrict__ x,
                                            const float* __restrict__ Wq,
                                            const float* __restrict__ Wp,
                                            const float* __restrict__ y,
                                            const float* __restrict__ Wkv,
                                            f16* __restrict__ xf,
                                            f16* __restrict__ wqhi, f16* __restrict__ wqlo,
                                            f16* __restrict__ wph,
                                            u16* __restrict__ yhi, u16* __restrict__ ylo,
                                            u16* __restrict__ wkhi, u16* __restrict__ wklo,
                                            int nx4, int nw4, int ny4, int nwk4) {
    int i = blockIdx.x * 256 + threadIdx.x;
    if (i < nx4) {
        f32x4 v = reinterpret_cast<const f32x4*>(x)[i];
        f16x4 h = {(f16)v[0], (f16)v[1], (f16)v[2], (f16)v[3]};
        reinterpret_cast<f16x4*>(xf)[i] = h;
    } else if (i < nx4 + nw4) {
        int k = i - nx4;
        f32x4 v = reinterpret_cast<const f32x4*>(Wq)[k];
        f16x4 H, L;
#pragma unroll
        for (int j = 0; j < 4; j++) {
            f16 hb = (f16)v[j];
            H[j] = hb;
            L[j] = (f16)(v[j] - (float)hb);
        }
        reinterpret_cast<f16x4*>(wqhi)[k] = H;
        reinterpret_cast<f16x4*>(wqlo)[k] = L;
    } else if (i < nx4 + 2 * nw4) {
        int k = i - nx4 - nw4;
        f32x4 v = reinterpret_cast<const f32x4*>(Wp)[k];
        f16x4 h = {(f16)v[0], (f16)v[1], (f16)v[2], (f16)v[3]};
        reinterpret_cast<f16x4*>(wph)[k] = h;
    } else if (i < nx4 + 2 * nw4 + ny4) {
        int k = i - nx4 - 2 * nw4;
        split4_store(y, yhi, ylo, k);
    } else {
        int k = i - nx4 - 2 * nw4 - ny4;
        if (k < nwk4) split4_store(Wkv, wkhi, wklo, k);
    }
}

// XCD-colocating remap for 852-block grids (213 m-tiles x 4 sub-groups).
// Blocks 8 apart in blockIdx land on the SAME XCD; the 4 sub-group blocks
// of one m-tile are placed at stride 8 so they share one XCD's L2.
// (Measured round-3/4: FETCH_SIZE 121 MB -> 63 MB on gemm_q.)
__device__ __forceinline__ void remap852(int j, int& mt, int& sg) {
    if (j < 832) {
        int a = j >> 5, rem = j & 31;
        mt = a * 8 + (rem & 7);   // [0,207]
        sg = rem >> 3;            // [0,3]
    } else {
        int rem = j - 832;
        mt = 208 + rem % 5;       // [208,212]
        sg = rem / 5;             // [0,3]
    }
}

// freqs for cross RoPE: 10000^(-f/16) = 10^(-f/4)
__constant__ double FREQS16[16] = {
    1.0, 0.5623413251903491, 0.31622776601683794, 0.17782794100389228,
    0.1, 0.05623413251903491, 0.03162277660168379, 0.017782794100389228,
    0.01, 0.005623413251903491, 0.0031622776601683794, 0.0017782794100389228,
    0.001, 0.0005623413251903491, 0.00031622776601683794, 0.00017782794100389228};

// ---------------------------------------------------------------------------
// Fused q projection (round-9 best: BK=128, 64-row m-tiles, 852 blocks).
// A = f16(x) staged via global_load_lds (XOR-swizzled, dbl-buffered 32 KB),
// W = f16 hi/lo direct. 2 MFMA per fragment. L2 norm, RoPE, f16 out.
// ---------------------------------------------------------------------------
__global__ __launch_bounds__(256) void gemm_q(const f16* __restrict__ xf,
                                              const f16* __restrict__ whi,
                                              const f16* __restrict__ wlo,
                                              const float* __restrict__ qb,
                                              const float* __restrict__ fc,
                                              const float* __restrict__ smul,
                                              f16* __restrict__ qout) {
    const int K = 1024, L = 1704;
    __shared__ f16 xs[2][2][64][64];  // [buf][khalf][row][k] = 32 KB (swizzled)
    int tid = threadIdx.x;
    int lane = tid & 63, wv = tid >> 6;        // wv = 0..3
    int mt, hg;
    remap852(blockIdx.x, mt, hg);
    int h  = hg * 4 + wv;
    int lr = lane & 15, quad = lane >> 4;
    long m0 = (long)mt * 64;

    int r0 = tid >> 3, c0 = tid & 7;
    int s1i = tid + 256;
    int r1 = s1i >> 3, c1 = s1i & 7;
    const f16* srcx0 = xf + (m0 + r0) * K + ((c0 ^ (r0 & 7)) * 8);
    const f16* srcx1 = xf + (m0 + r1) * K + ((c1 ^ (r1 & 7)) * 8);
    f16* dx[2][2][2];  // [buf][khalf][slot]
#pragma unroll
    for (int b = 0; b < 2; b++)
#pragma unroll
        for (int hh = 0; hh < 2; hh++) {
            dx[b][hh][0] = &xs[b][hh][r0][c0 * 8];
            dx[b][hh][1] = &xs[b][hh][r1][c1 * 8];
        }

    const f16x8* wh_p[4];
    const f16x8* wl_p[4];
#pragma unroll
    for (int i = 0; i < 4; i++) {
        long woff = ((long)(h * 64 + i * 16 + lr)) * K;
        wh_p[i] = reinterpret_cast<const f16x8*>(whi + woff) + quad;
        wl_p[i] = reinterpret_cast<const f16x8*>(wlo + woff) + quad;
    }

    int sp0 = ((0 + quad) ^ (lr & 7)) * 8;
    int sp1 = ((4 + quad) ^ (lr & 7)) * 8;

    f32x4 acc[4][4] = {};

    async_cp16(dx[0][0][0], srcx0);      async_cp16(dx[0][0][1], srcx1);
    async_cp16(dx[0][1][0], srcx0 + 64); async_cp16(dx[0][1][1], srcx1 + 64);
    __syncthreads();

    for (int c = 0; c < 8; c++) {
        if (c < 7) {
            int nb = (c + 1) & 1;
            int off = (c + 1) * 128;
            async_cp16(dx[nb][0][0], srcx0 + off);      async_cp16(dx[nb][0][1], srcx1 + off);
            async_cp16(dx[nb][1][0], srcx0 + off + 64); async_cp16(dx[nb][1][1], srcx1 + off + 64);
        }
        int buf = c & 1;
#pragma unroll
        for (int hh = 0; hh < 2; hh++) {
#pragma unroll
            for (int s = 0; s < 2; s++) {
                int o = (c * 2 + hh) * 8 + s * 4;
                int sp = s ? sp1 : sp0;
                f16x8 AF[4], WH[4], WL[4];
#pragma unroll
                for (int i = 0; i < 4; i++) {
                    WH[i] = wh_p[i][o];
                    WL[i] = wl_p[i][o];
                }
#pragma unroll
                for (int i = 0; i < 4; i++)
                    AF[i] = *reinterpret_cast<const f16x8*>(&xs[buf][hh][i * 16 + lr][sp]);
#pragma unroll
                for (int mi = 0; mi < 4; mi++)
#pragma unroll
                    for (int ni = 0; ni < 4; ni++) {
                        acc[mi][ni] = __builtin_amdgcn_mfma_f32_16x16x32_f16(AF[mi], WH[ni], acc[mi][ni], 0, 0, 0);
                        acc[mi][ni] = __builtin_amdgcn_mfma_f32_16x16x32_f16(AF[mi], WL[ni], acc[mi][ni], 0, 0, 0);
                    }
            }
        }
        __syncthreads();  // waves done reading buf; staged c+1 drained
    }

    float sm = __expf(fminf(smul[h], 4.6051702f));  // ln(100)
#pragma unroll
    for (int mi = 0; mi < 4; mi++) {
#pragma unroll
        for (int r = 0; r < 4; r++) {
            long rowg = m0 + mi * 16 + quad * 4 + r;
            float v[4];
            float ss = 0.f;
#pragma unroll
            for (int ni = 0; ni < 4; ni++) {
                v[ni] = acc[mi][ni][r] + qb[h * 64 + ni * 16 + lr];
                ss += v[ni] * v[ni];
            }
            ss += __shfl_xor(ss, 1, 64); ss += __shfl_xor(ss, 2, 64);
            ss += __shfl_xor(ss, 4, 64); ss += __shfl_xor(ss, 8, 64);
            float inv = sm / fmaxf(sqrtf(ss), 1e-12f);
            int l = (int)(rowg % L);
            f16* orow = qout + rowg * 1024 + h * 64;
#pragma unroll
            for (int ni = 0; ni < 4; ni++) {
                float u = v[ni] * inv;
                int d = ni * 16 + lr;
                int j = d >> 1;
                float c = fc[(l * 32 + j) * 2];
                float s = fc[(l * 32 + j) * 2 + 1];
                float pr = __shfl_xor(u, 1, 64);
                float o = (lane & 1) ? (pr * s + u * c) : (u * c - pr * s);
                orow[d] = (f16)o;
            }
        }
    }
}

// ---------------------------------------------------------------------------
// Fused kv projection (round-9): pre-split bf16 hi/lo planes, no LDS,
// 32-row m-tiles, 288 blocks. Bit-identical k/v.
// ---------------------------------------------------------------------------
__global__ __launch_bounds__(256) void gemm_kv(const u16* __restrict__ yhi,
                                               const u16* __restrict__ ylo,
                                               const u16* __restrict__ wkhi,
                                               const u16* __restrict__ wklo,
                                               const float* __restrict__ vb,
                                               f16* __restrict__ khp,
                                               f16* __restrict__ klp,
                                               f16* __restrict__ vhp,
                                               f16* __restrict__ vlp) {
    const int K = 1024;
    int lane = threadIdx.x & 63, wv = threadIdx.x >> 6;
    int mt = blockIdx.x >> 3;            // [0,36)
    int nt = (blockIdx.x & 7) * 4 + wv;  // [0,32)
    int lr = lane & 15, quad = lane >> 4;
    long m0 = (long)mt * 32;

    const bf16x8* ah_p[2];
    const bf16x8* al_p[2];
    const bf16x8* wh_p[4];
    const bf16x8* wl_p[4];
#pragma unroll
    for (int i = 0; i < 2; i++) {
        long aoff = (m0 + i * 16 + lr) * K;
        ah_p[i] = reinterpret_cast<const bf16x8*>(yhi + aoff) + quad;
        al_p[i] = reinterpret_cast<const bf16x8*>(ylo + aoff) + quad;
    }
#pragma unroll
    for (int i = 0; i < 4; i++) {
        long woff = ((long)(nt * 64 + i * 16 + lr)) * K;
        wh_p[i] = reinterpret_cast<const bf16x8*>(wkhi + woff) + quad;
        wl_p[i] = reinterpret_cast<const bf16x8*>(wklo + woff) + quad;
    }

    f32x4 acc[2][4] = {};
    for (int ks = 0; ks < 32; ks++) {
        int o = ks * 4;
        bf16x8 ah[2], al[2], wh[4], wl[4];
#pragma unroll
        for (int i = 0; i < 2; i++) { ah[i] = ah_p[i][o]; al[i] = al_p[i][o]; }
#pragma unroll
        for (int i = 0; i < 4; i++) { wh[i] = wh_p[i][o]; wl[i] = wl_p[i][o]; }
#pragma unroll
        for (int mi = 0; mi < 2; mi++)
#pragma unroll
            for (int ni = 0; ni < 4; ni++) {
                acc[mi][ni] = __builtin_amdgcn_mfma_f32_16x16x32_bf16(ah[mi], wh[ni], acc[mi][ni], 0, 0, 0);
                acc[mi][ni] = __builtin_amdgcn_mfma_f32_16x16x32_bf16(al[mi], wh[ni], acc[mi][ni], 0, 0, 0);
                acc[mi][ni] = __builtin_amdgcn_mfma_f32_16x16x32_bf16(ah[mi], wl[ni], acc[mi][ni], 0, 0, 0);
            }
    }

    bool isv = nt >= 16;
    int h = isv ? nt - 16 : nt;
#pragma unroll
    for (int mi = 0; mi < 2; mi++) {
#pragma unroll
        for (int r = 0; r < 4; r++) {
            long row = m0 + mi * 16 + quad * 4 + r;  // [0,1152)
            int b = (int)(row / 144), lk = (int)(row % 144);
            long bh = b * 16 + h;
            float v[4];
#pragma unroll
            for (int ni = 0; ni < 4; ni++)
                v[ni] = acc[mi][ni][r] + (isv ? vb[h * 64 + ni * 16 + lr] : 0.f);
            if (!isv) {
                float ss = v[0] * v[0] + v[1] * v[1] + v[2] * v[2] + v[3] * v[3];
                ss += __shfl_xor(ss, 1, 64); ss += __shfl_xor(ss, 2, 64);
                ss += __shfl_xor(ss, 4, 64); ss += __shfl_xor(ss, 8, 64);
                float inv = 1.f / fmaxf(sqrtf(ss), 1e-12f);
                f16* kh_row = khp + (bh * 144 + lk) * 64;
                f16* kl_row = klp + (bh * 144 + lk) * 64;
#pragma unroll
                for (int ni = 0; ni < 4; ni++) {
                    float u = v[ni] * inv;
                    int d = ni * 16 + lr;
                    int j = d >> 1;
                    int f = j & 15;
                    float tc = (j < 16) ? ((float)(lk / 12)) / 12.0f * 32.0f
                                        : ((float)(lk % 12)) / 12.0f * 32.0f;
                    float ang = (float)((double)tc * FREQS16[f]);
                    float c = cosf(ang), s = sinf(ang);
                    float pr = __shfl_xor(u, 1, 64);
                    float o = (lane & 1) ? (pr * s + u * c) : (u * c - pr * s);
                    f16 oh = (f16)o;
                    f16 ol = (f16)(o - (float)oh);
                    kh_row[d] = oh;
                    kl_row[d] = ol;
                }
            } else {
#pragma unroll
                for (int ni = 0; ni < 4; ni++) {
                    float val = v[ni];
                    int d = ni * 16 + lr;
                    f16 vh = (f16)val;
                    f16 vl = (f16)(val - (float)vh);
                    vhp[(bh * 64 + d) * 144 + lk] = vh;
                    vlp[(bh * 64 + d) * 144 + lk] = vl;
                }
            }
        }
    }
}

// ---------------------------------------------------------------------------
// MFMA attention. NEW: XCD-colocating block remap — all 27 l-tile blocks of
// one (b,h) share one XCD's L2 (K/V planes fetched once per XCD instead of
// 8x; same mechanism as remap852's measured 2x FETCH drop on gemm_q).
// xcd = j&7; idx = j>>3; bh = (idx/27)*8 + xcd; ltile = idx%27.
// Bijective over 3456 = 8 * (16*27). Compute unchanged (bit-identical).
// ---------------------------------------------------------------------------
__global__ __launch_bounds__(256, 3) void attn(const f16* q,
                                               const f16* __restrict__ khp,
                                               const f16* __restrict__ klp,
                                               const f16* __restrict__ vhp,
                                               const f16* __restrict__ vlp,
                                               const float* __restrict__ abias,
                                               f16* aout) {
    const int L = 1704;
    __shared__ __align__(16) f16 ps[4][16][152];  // 19.5 KB, per-wave regions
    int tid = threadIdx.x;
    int lane = tid & 63, wv = tid >> 6;
    int lr = lane & 15, quad = lane >> 4;
    int j = blockIdx.x;
    int xcd = j & 7;
    int idx = j >> 3;               // 0..431
    int bh = (idx / 27) * 8 + xcd;  // 0..127, colocated per XCD
    int ltile = idx % 27;
    int h = bh & 15, b = bh >> 4;
    int l0 = ltile * 64;
    int rows = min(64, L - l0);  // 64 or 40 (tail)

    int rA = wv * 16 + lr;
    int rAc = min(rA, rows - 1);
    const f16* qrow = q + ((long)(b * L + l0 + rAc)) * 1024 + h * 64;
    f16x8 qa0 = *reinterpret_cast<const f16x8*>(qrow + quad * 8);
    f16x8 qa1 = *reinterpret_cast<const f16x8*>(qrow + 32 + quad * 8);

    const f16* khb = khp + (long)bh * (144 * 64);
    const f16* klb = klp + (long)bh * (144 * 64);

    f32x4 acc[9] = {};
#pragma unroll
    for (int t = 0; t < 9; t++) {
        const f16* k0 = khb + (t * 16 + lr) * 64 + quad * 8;
        const f16* k1 = klb + (t * 16 + lr) * 64 + quad * 8;
        f16x8 bh0 = *reinterpret_cast<const f16x8*>(k0);
        f16x8 bh1 = *reinterpret_cast<const f16x8*>(k0 + 32);
        f16x8 bl0 = *reinterpret_cast<const f16x8*>(k1);
        f16x8 bl1 = *reinterpret_cast<const f16x8*>(k1 + 32);
        __builtin_amdgcn_s_setprio(1);
        acc[t] = __builtin_amdgcn_mfma_f32_16x16x32_f16(qa0, bh0, acc[t], 0, 0, 0);
        acc[t] = __builtin_amdgcn_mfma_f32_16x16x32_f16(qa1, bh1, acc[t], 0, 0, 0);
        acc[t] = __builtin_amdgcn_mfma_f32_16x16x32_f16(qa0, bl0, acc[t], 0, 0, 0);
        acc[t] = __builtin_amdgcn_mfma_f32_16x16x32_f16(qa1, bl1, acc[t], 0, 0, 0);
        __builtin_amdgcn_s_setprio(0);
    }

    int rC = wv * 16 + quad * 4;
#pragma unroll
    for (int r = 0; r < 4; r++) {
        long lrow = (long)(l0 + min(rC + r, rows - 1)) * 144;
#pragma unroll
        for (int t = 0; t < 9; t++) acc[t][r] += abias[lrow + t * 16 + lr];
    }

#pragma unroll
    for (int r = 0; r < 4; r++) {
        float mx = acc[0][r];
#pragma unroll
        for (int t = 1; t < 9; t++) mx = fmaxf(mx, acc[t][r]);
        mx = fmaxf(mx, __shfl_xor(mx, 1, 64));
        mx = fmaxf(mx, __shfl_xor(mx, 2, 64));
        mx = fmaxf(mx, __shfl_xor(mx, 4, 64));
        mx = fmaxf(mx, __shfl_xor(mx, 8, 64));
        float s = 0.f;
#pragma unroll
        for (int t = 0; t < 9; t++) {
            float e = __expf(acc[t][r] - mx);
            acc[t][r] = e;
            s += e;
        }
        s += __shfl_xor(s, 1, 64);
        s += __shfl_xor(s, 2, 64);
        s += __shfl_xor(s, 4, 64);
        s += __shfl_xor(s, 8, 64);
        float inv = 1.0f / s;
#pragma unroll
        for (int t = 0; t < 9; t++)
            ps[wv][quad * 4 + r][t * 16 + lr] = (f16)(acc[t][r] * inv);
    }

    const f16* vhb = vhp + (long)bh * (64 * 144);
    const f16* vlb = vlp + (long)bh * (64 * 144);
    f32x4 oacc[4] = {};
#pragma unroll
    for (int ks = 0; ks < 5; ks++) {
        f16x8 pa = {0, 0, 0, 0, 0, 0, 0, 0};
        if (ks < 4 || quad < 2)
            pa = *reinterpret_cast<const f16x8*>(&ps[wv][lr][ks * 32 + quad * 8]);
#pragma unroll
        for (int n = 0; n < 4; n++) {
            f16x8 vh8 = {0, 0, 0, 0, 0, 0, 0, 0};
            f16x8 vl8 = {0, 0, 0, 0, 0, 0, 0, 0};
            if (ks < 4 || quad < 2) {
                const f16* vr  = vhb + (n * 16 + lr) * 144 + ks * 32 + quad * 8;
                const f16* vr2 = vlb + (n * 16 + lr) * 144 + ks * 32 + quad * 8;
                vh8 = *reinterpret_cast<const f16x8*>(vr);
                vl8 = *reinterpret_cast<const f16x8*>(vr2);
            }
            __builtin_amdgcn_s_setprio(1);
            oacc[n] = __builtin_amdgcn_mfma_f32_16x16x32_f16(pa, vh8, oacc[n], 0, 0, 0);
            oacc[n] = __builtin_amdgcn_mfma_f32_16x16x32_f16(pa, vl8, oacc[n], 0, 0, 0);
            __builtin_amdgcn_s_setprio(0);
        }
    }

    long ob = (long)(b * L + l0);
#pragma unroll
    for (int r = 0; r < 4; r++) {
        int rw = rC + r;
        if (rw < rows) {
            f16* ao = aout + (ob + rw) * 1024 + h * 64;
#pragma unroll
            for (int n = 0; n < 4; n++) ao[n * 16 + lr] = (f16)oacc[n][r];
        }
    }
}

// ---------------------------------------------------------------------------
// Final projection (round-9 best: BK=128, 64-row m-tiles, 852 blocks,
// remap852). A f16 staged (dbl-buffered 32 KB, swizzled), W f16 direct.
// ---------------------------------------------------------------------------
__global__ __launch_bounds__(256) void gemm_proj(const f16* __restrict__ A,
                                                 const f16* __restrict__ Wh,
                                                 const float* __restrict__ bias,
                                                 float* __restrict__ out) {
    const int K = 1024;
    __shared__ f16 as[2][2][64][64];  // [buf][khalf][row][k] = 32 KB (swizzled)
    int tid = threadIdx.x;
    int lane = tid & 63, wv = tid >> 6;
    int mt, cg;
    remap852(blockIdx.x, mt, cg);
    int lr = lane & 15, quad = lane >> 4;
    long m0 = (long)mt * 64;
    long n0 = (long)cg * 256 + wv * 64;

    int r0 = tid >> 3, c0 = tid & 7;
    int s1i = tid + 256;
    int r1 = s1i >> 3, c1 = s1i & 7;
    const f16* srca0 = A + (m0 + r0) * K + ((c0 ^ (r0 & 7)) * 8);
    const f16* srca1 = A + (m0 + r1) * K + ((c1 ^ (r1 & 7)) * 8);
    f16* da[2][2][2];
#pragma unroll
    for (int b = 0; b < 2; b++)
#pragma unroll
        for (int hh = 0; hh < 2; hh++) {
            da[b][hh][0] = &as[b][hh][r0][c0 * 8];
            da[b][hh][1] = &as[b][hh][r1][c1 * 8];
        }

    const f16x8* wrow[4];
#pragma unroll
    for (int i = 0; i < 4; i++)
        wrow[i] = reinterpret_cast<const f16x8*>(Wh + (n0 + i * 16 + lr) * K) + quad;

    int sp0 = ((0 + quad) ^ (lr & 7)) * 8;
    int sp1 = ((4 + quad) ^ (lr & 7)) * 8;

    f32x4 acc[4][4] = {};

    async_cp16(da[0][0][0], srca0);      async_cp16(da[0][0][1], srca1);
    async_cp16(da[0][1][0], srca0 + 64); async_cp16(da[0][1][1], srca1 + 64);
    __syncthreads();

    for (int c = 0; c < 8; c++) {
        if (c < 7) {
            int nb = (c + 1) & 1;
            int off = (c + 1) * 128;
            async_cp16(da[nb][0][0], srca0 + off);      async_cp16(da[nb][0][1], srca1 + off);
            async_cp16(da[nb][1][0], srca0 + off + 64); async_cp16(da[nb][1][1], srca1 + off + 64);
        }
        int buf = c & 1;
#pragma unroll
        for (int hh = 0; hh < 2; hh++) {
#pragma unroll
            for (int s = 0; s < 2; s++) {
                int o = (c * 2 + hh) * 8 + s * 4;
                int sp = s ? sp1 : sp0;
                f16x8 af[4], wf[4];
#pragma unroll
                for (int i = 0; i < 4; i++) wf[i] = wrow[i][o];
#pragma unroll
                for (int i = 0; i < 4; i++)
                    af[i] = *reinterpret_cast<const f16x8*>(&as[buf][hh][i * 16 + lr][sp]);
#pragma unroll
                for (int mi = 0; mi < 4; mi++)
#pragma unroll
                    for (int ni = 0; ni < 4; ni++)
                        acc[mi][ni] = __builtin_amdgcn_mfma_f32_16x16x32_f16(af[mi], wf[ni], acc[mi][ni], 0, 0, 0);
            }
        }
        __syncthreads();
    }

#pragma unroll
    for (int ni = 0; ni < 4; ni++) {
        int col = (int)n0 + ni * 16 + lr;
        float b = bias[col];
#pragma unroll
        for (int mi = 0; mi < 4; mi++) {
            long row = m0 + mi * 16 + quad * 4;
#pragma unroll
            for (int r = 0; r < 4; r++)
                out[(row + r) * 1024 + col] = acc[mi][ni][r] + b;
        }
    }
}

extern "C" void kernel_launch(void* const* d_in, const int* in_sizes, int n_in,
                              void* d_out, int out_size, void* d_ws, size_t ws_size,
                              hipStream_t stream) {
    const float* x     = (const float*)d_in[0];
    const float* y     = (const float*)d_in[1];
    const float* fc    = (const float*)d_in[2];
    const float* abias = (const float*)d_in[3];
    const float* Wq    = (const float*)d_in[4];
    const float* qb    = (const float*)d_in[5];
    const float* Wkv   = (const float*)d_in[6];
    const float* vb    = (const float*)d_in[7];
    const float* Wp    = (const float*)d_in[8];
    const float* bp    = (const float*)d_in[9];
    const float* smul  = (const float*)d_in[10];

    const long XN  = 13959168L;  // 8*1704*1024
    const long WN  = 1048576L;   // 1024*1024
    const long YN  = 1179648L;   // 8*144*1024
    const long WKN = 2097152L;   // 2048*1024
    const long KVN = 1179648L;   // 128*144*64 (= 128*64*144)

    // d_ws layout (33.9 MB): qbuf fp16 | Wq hi f16 | Wq lo f16 | Wp fp16
    f16* qbuf  = (f16*)d_ws;
    f16* wq_hi = qbuf + XN;
    f16* wq_lo = wq_hi + WN;
    f16* wp_h  = wq_lo + WN;

    // d_out (55.8 MB) phase 1 (41.1 MB used):
    //   x f16 plane (27.9 MB) | y bf16 hi/lo (2x2.36 MB) | Wkv bf16 hi/lo (2x4.2 MB)
    // x_f dead after gemm_q; y/Wkv planes dead after gemm_kv.
    f16* x_f   = (f16*)d_out;
    u16* y_hi  = (u16*)(x_f + XN);
    u16* y_lo  = y_hi + YN;
    u16* wk_hi = y_lo + YN;
    u16* wk_lo = wk_hi + WKN;
    // d_out phase 2: K/V f16 planes (9.4 MB) at offset 0 (over dead x_f);
    // dead after attn; overwritten by gemm_proj's fp32 output.
    f16* kh_p  = (f16*)d_out;
    f16* kl_p  = kh_p + KVN;
    f16* vth_p = kl_p + KVN;
    f16* vtl_p = vth_p + KVN;

    int nx4  = (int)(XN / 4);
    int nw4  = (int)(WN / 4);
    int ny4  = (int)(YN / 4);
    int nwk4 = (int)(WKN / 4);
    int prep_blocks = (nx4 + 2 * nw4 + ny4 + nwk4 + 255) / 256;

    prep<<<dim3(prep_blocks), dim3(256), 0, stream>>>(
        x, Wq, Wp, y, Wkv, x_f, wq_hi, wq_lo, wp_h,
        y_hi, y_lo, wk_hi, wk_lo, nx4, nw4, ny4, nwk4);
    gemm_q<<<dim3(852), dim3(256), 0, stream>>>(x_f, wq_hi, wq_lo, qb, fc, smul, qbuf);
    gemm_kv<<<dim3(288), dim3(256), 0, stream>>>(y_hi, y_lo, wk_hi, wk_lo, vb,
                                                 kh_p, kl_p, vth_p, vtl_p);
    attn<<<dim3(3456), dim3(256), 0, stream>>>(qbuf, kh_p, kl_p, vth_p, vtl_p, abias, (f16*)qbuf);
    gemm_proj<<<dim3(852), dim3(256), 0, stream>>>((const f16*)qbuf, wp_h, bp, (float*)d_out);
}

// Round 12
// 485.925 us; speedup vs baseline: 1.2444x; 1.1100x over previous
//
#include <hip/hip_runtime.h>

using u16 = unsigned short;
using u32 = unsigned int;

typedef __bf16 bf16x8 __attribute__((ext_vector_type(8)));
typedef float  f32x4  __attribute__((ext_vector_type(4)));
typedef _Float16 f16;
typedef _Float16 f16x4 __attribute__((ext_vector_type(4)));
typedef _Float16 f16x8 __attribute__((ext_vector_type(8)));
typedef u16 u16x4 __attribute__((ext_vector_type(4)));

__device__ __forceinline__ float b2f(u16 u) { return __uint_as_float(((u32)u) << 16); }
__device__ __forceinline__ u16 f2b(float f) {
    u32 u = __float_as_uint(f);
    return (u16)((u + 0x7FFFu + ((u >> 16) & 1u)) >> 16);  // RNE
}

// async global->LDS, 16 B per lane.
__device__ __forceinline__ void async_cp16(void* lds, const void* g) {
    __builtin_amdgcn_global_load_lds(
        (const __attribute__((address_space(1))) u32*)g,
        (__attribute__((address_space(3))) u32*)lds, 16, 0, 0);
}

// fp32x4 -> (hi, lo) bf16 planes (bit-identical to old in-kernel split8)
__device__ __forceinline__ void split4_store(const float* src, u16* hi, u16* lo, int i) {
    f32x4 v = reinterpret_cast<const f32x4*>(src)[i];
    u16x4 H, L;
#pragma unroll
    for (int j = 0; j < 4; j++) {
        u16 hb = f2b(v[j]);
        H[j] = hb;
        L[j] = f2b(v[j] - b2f(hb));
    }
    reinterpret_cast<u16x4*>(hi)[i] = H;
    reinterpret_cast<u16x4*>(lo)[i] = L;
}

// ---------------------------------------------------------------------------
// Fused prep: x->f16; Wq->f16 hi/lo; Wp->f16; y->bf16 hi/lo; Wkv->bf16 hi/lo
// ---------------------------------------------------------------------------
__global__ __launch_bounds__(256) void prep(const float* __restrict__ x,
                                            const float* __restrict__ Wq,
                                            const float* __restrict__ Wp,
                                            const float* __restrict__ y,
                                            const float* __restrict__ Wkv,
                                            f16* __restrict__ xf,
                                            f16* __restrict__ wqhi, f16* __restrict__ wqlo,
                                            f16* __restrict__ wph,
                                            u16* __restrict__ yhi, u16* __restrict__ ylo,
                                            u16* __restrict__ wkhi, u16* __restrict__ wklo,
                                            int nx4, int nw4, int ny4, int nwk4) {
    int i = blockIdx.x * 256 + threadIdx.x;
    if (i < nx4) {
        f32x4 v = reinterpret_cast<const f32x4*>(x)[i];
        f16x4 h = {(f16)v[0], (f16)v[1], (f16)v[2], (f16)v[3]};
        reinterpret_cast<f16x4*>(xf)[i] = h;
    } else if (i < nx4 + nw4) {
        int k = i - nx4;
        f32x4 v = reinterpret_cast<const f32x4*>(Wq)[k];
        f16x4 H, L;
#pragma unroll
        for (int j = 0; j < 4; j++) {
            f16 hb = (f16)v[j];
            H[j] = hb;
            L[j] = (f16)(v[j] - (float)hb);
        }
        reinterpret_cast<f16x4*>(wqhi)[k] = H;
        reinterpret_cast<f16x4*>(wqlo)[k] = L;
    } else if (i < nx4 + 2 * nw4) {
        int k = i - nx4 - nw4;
        f32x4 v = reinterpret_cast<const f32x4*>(Wp)[k];
        f16x4 h = {(f16)v[0], (f16)v[1], (f16)v[2], (f16)v[3]};
        reinterpret_cast<f16x4*>(wph)[k] = h;
    } else if (i < nx4 + 2 * nw4 + ny4) {
        int k = i - nx4 - 2 * nw4;
        split4_store(y, yhi, ylo, k);
    } else {
        int k = i - nx4 - 2 * nw4 - ny4;
        if (k < nwk4) split4_store(Wkv, wkhi, wklo, k);
    }
}

// XCD-colocating remap for 852-block grids (213 m-tiles x 4 sub-groups).
// Blocks 8 apart in blockIdx land on the SAME XCD; the 4 sub-group blocks
// of one m-tile are placed at stride 8 so they share one XCD's L2.
// (Measured round-3/4: FETCH_SIZE 121 MB -> 63 MB on gemm_q.)
__device__ __forceinline__ void remap852(int j, int& mt, int& sg) {
    if (j < 832) {
        int a = j >> 5, rem = j & 31;
        mt = a * 8 + (rem & 7);   // [0,207]
        sg = rem >> 3;            // [0,3]
    } else {
        int rem = j - 832;
        mt = 208 + rem % 5;       // [208,212]
        sg = rem / 5;             // [0,3]
    }
}

// freqs for cross RoPE: 10000^(-f/16) = 10^(-f/4)
__constant__ double FREQS16[16] = {
    1.0, 0.5623413251903491, 0.31622776601683794, 0.17782794100389228,
    0.1, 0.05623413251903491, 0.03162277660168379, 0.017782794100389228,
    0.01, 0.005623413251903491, 0.0031622776601683794, 0.0017782794100389228,
    0.001, 0.0005623413251903491, 0.00031622776601683794, 0.00017782794100389228};

// ---------------------------------------------------------------------------
// FUSED q + kv projections, ISOLATED fusion (round-10 retry with the q path
// kept EXACTLY at the round-9 best: 64-row m-tiles, BK=128, 852 blocks).
// Rationale: gemm_q is latency-bound at 17% occupancy (83% of wave slots
// idle); kv's 288 independent blocks fill those slots and run in q's
// latency shadow instead of serially after it.
// blockIdx < 288 : kv path (round-9 code, pre-split bf16 planes, no LDS).
// blockIdx >= 288: q path, remap852(blockIdx-288); 288%8==0 so the XCD
// colocation mapping is identical to the standalone round-9 kernel.
// Per-element arithmetic identical -> bit-identical q and k/v.
// ---------------------------------------------------------------------------
__global__ __launch_bounds__(256) void qkv(const f16* __restrict__ xf,
                                           const f16* __restrict__ whi,
                                           const f16* __restrict__ wlo,
                                           const float* __restrict__ qb,
                                           const float* __restrict__ fc,
                                           const float* __restrict__ smul,
                                           f16* __restrict__ qout,
                                           const u16* __restrict__ yhi,
                                           const u16* __restrict__ ylo,
                                           const u16* __restrict__ wkhi,
                                           const u16* __restrict__ wklo,
                                           const float* __restrict__ vb,
                                           f16* __restrict__ khp,
                                           f16* __restrict__ klp,
                                           f16* __restrict__ vhp,
                                           f16* __restrict__ vlp) {
    const int K = 1024, L = 1704;
    __shared__ f16 xs[2][2][64][64];  // [buf][khalf][row][k] = 32 KB (swizzled)
    int tid = threadIdx.x;
    int lane = tid & 63, wv = tid >> 6;
    int lr = lane & 15, quad = lane >> 4;

    if (blockIdx.x < 288) {
        // ------------------------- KV path (round-9) -------------------------
        int mt = blockIdx.x >> 3;            // [0,36)
        int nt = (blockIdx.x & 7) * 4 + wv;  // [0,32)
        long m0 = (long)mt * 32;

        const bf16x8* ah_p[2];
        const bf16x8* al_p[2];
        const bf16x8* wh_p[4];
        const bf16x8* wl_p[4];
#pragma unroll
        for (int i = 0; i < 2; i++) {
            long aoff = (m0 + i * 16 + lr) * K;
            ah_p[i] = reinterpret_cast<const bf16x8*>(yhi + aoff) + quad;
            al_p[i] = reinterpret_cast<const bf16x8*>(ylo + aoff) + quad;
        }
#pragma unroll
        for (int i = 0; i < 4; i++) {
            long woff = ((long)(nt * 64 + i * 16 + lr)) * K;
            wh_p[i] = reinterpret_cast<const bf16x8*>(wkhi + woff) + quad;
            wl_p[i] = reinterpret_cast<const bf16x8*>(wklo + woff) + quad;
        }

        f32x4 acc[2][4] = {};
        for (int ks = 0; ks < 32; ks++) {
            int o = ks * 4;
            bf16x8 ah[2], al[2], wh[4], wl[4];
#pragma unroll
            for (int i = 0; i < 2; i++) { ah[i] = ah_p[i][o]; al[i] = al_p[i][o]; }
#pragma unroll
            for (int i = 0; i < 4; i++) { wh[i] = wh_p[i][o]; wl[i] = wl_p[i][o]; }
#pragma unroll
            for (int mi = 0; mi < 2; mi++)
#pragma unroll
                for (int ni = 0; ni < 4; ni++) {
                    acc[mi][ni] = __builtin_amdgcn_mfma_f32_16x16x32_bf16(ah[mi], wh[ni], acc[mi][ni], 0, 0, 0);
                    acc[mi][ni] = __builtin_amdgcn_mfma_f32_16x16x32_bf16(al[mi], wh[ni], acc[mi][ni], 0, 0, 0);
                    acc[mi][ni] = __builtin_amdgcn_mfma_f32_16x16x32_bf16(ah[mi], wl[ni], acc[mi][ni], 0, 0, 0);
                }
        }

        bool isv = nt >= 16;
        int h = isv ? nt - 16 : nt;
#pragma unroll
        for (int mi = 0; mi < 2; mi++) {
#pragma unroll
            for (int r = 0; r < 4; r++) {
                long row = m0 + mi * 16 + quad * 4 + r;  // [0,1152)
                int b = (int)(row / 144), lk = (int)(row % 144);
                long bh = b * 16 + h;
                float v[4];
#pragma unroll
                for (int ni = 0; ni < 4; ni++)
                    v[ni] = acc[mi][ni][r] + (isv ? vb[h * 64 + ni * 16 + lr] : 0.f);
                if (!isv) {
                    float ss = v[0] * v[0] + v[1] * v[1] + v[2] * v[2] + v[3] * v[3];
                    ss += __shfl_xor(ss, 1, 64); ss += __shfl_xor(ss, 2, 64);
                    ss += __shfl_xor(ss, 4, 64); ss += __shfl_xor(ss, 8, 64);
                    float inv = 1.f / fmaxf(sqrtf(ss), 1e-12f);
                    f16* kh_row = khp + (bh * 144 + lk) * 64;
                    f16* kl_row = klp + (bh * 144 + lk) * 64;
#pragma unroll
                    for (int ni = 0; ni < 4; ni++) {
                        float u = v[ni] * inv;
                        int d = ni * 16 + lr;
                        int j = d >> 1;
                        int f = j & 15;
                        float tc = (j < 16) ? ((float)(lk / 12)) / 12.0f * 32.0f
                                            : ((float)(lk % 12)) / 12.0f * 32.0f;
                        float ang = (float)((double)tc * FREQS16[f]);
                        float c = cosf(ang), s = sinf(ang);
                        float pr = __shfl_xor(u, 1, 64);
                        float o = (lane & 1) ? (pr * s + u * c) : (u * c - pr * s);
                        f16 oh = (f16)o;
                        f16 ol = (f16)(o - (float)oh);
                        kh_row[d] = oh;
                        kl_row[d] = ol;
                    }
                } else {
#pragma unroll
                    for (int ni = 0; ni < 4; ni++) {
                        float val = v[ni];
                        int d = ni * 16 + lr;
                        f16 vh = (f16)val;
                        f16 vl = (f16)(val - (float)vh);
                        vhp[(bh * 64 + d) * 144 + lk] = vh;
                        vlp[(bh * 64 + d) * 144 + lk] = vl;
                    }
                }
            }
        }
        return;
    }

    // ---------------- Q path (round-9 best, unchanged) ----------------
    int mt, hg;
    remap852(blockIdx.x - 288, mt, hg);
    int h  = hg * 4 + wv;
    long m0 = (long)mt * 64;

    int r0 = tid >> 3, c0 = tid & 7;
    int s1i = tid + 256;
    int r1 = s1i >> 3, c1 = s1i & 7;
    const f16* srcx0 = xf + (m0 + r0) * K + ((c0 ^ (r0 & 7)) * 8);
    const f16* srcx1 = xf + (m0 + r1) * K + ((c1 ^ (r1 & 7)) * 8);
    f16* dx[2][2][2];  // [buf][khalf][slot]
#pragma unroll
    for (int b = 0; b < 2; b++)
#pragma unroll
        for (int hh = 0; hh < 2; hh++) {
            dx[b][hh][0] = &xs[b][hh][r0][c0 * 8];
            dx[b][hh][1] = &xs[b][hh][r1][c1 * 8];
        }

    const f16x8* wh_p[4];
    const f16x8* wl_p[4];
#pragma unroll
    for (int i = 0; i < 4; i++) {
        long woff = ((long)(h * 64 + i * 16 + lr)) * K;
        wh_p[i] = reinterpret_cast<const f16x8*>(whi + woff) + quad;
        wl_p[i] = reinterpret_cast<const f16x8*>(wlo + woff) + quad;
    }

    int sp0 = ((0 + quad) ^ (lr & 7)) * 8;
    int sp1 = ((4 + quad) ^ (lr & 7)) * 8;

    f32x4 acc[4][4] = {};

    async_cp16(dx[0][0][0], srcx0);      async_cp16(dx[0][0][1], srcx1);
    async_cp16(dx[0][1][0], srcx0 + 64); async_cp16(dx[0][1][1], srcx1 + 64);
    __syncthreads();

    for (int c = 0; c < 8; c++) {
        if (c < 7) {
            int nb = (c + 1) & 1;
            int off = (c + 1) * 128;
            async_cp16(dx[nb][0][0], srcx0 + off);      async_cp16(dx[nb][0][1], srcx1 + off);
            async_cp16(dx[nb][1][0], srcx0 + off + 64); async_cp16(dx[nb][1][1], srcx1 + off + 64);
        }
        int buf = c & 1;
#pragma unroll
        for (int hh = 0; hh < 2; hh++) {
#pragma unroll
            for (int s = 0; s < 2; s++) {
                int o = (c * 2 + hh) * 8 + s * 4;
                int sp = s ? sp1 : sp0;
                f16x8 AF[4], WH[4], WL[4];
#pragma unroll
                for (int i = 0; i < 4; i++) {
                    WH[i] = wh_p[i][o];
                    WL[i] = wl_p[i][o];
                }
#pragma unroll
                for (int i = 0; i < 4; i++)
                    AF[i] = *reinterpret_cast<const f16x8*>(&xs[buf][hh][i * 16 + lr][sp]);
#pragma unroll
                for (int mi = 0; mi < 4; mi++)
#pragma unroll
                    for (int ni = 0; ni < 4; ni++) {
                        acc[mi][ni] = __builtin_amdgcn_mfma_f32_16x16x32_f16(AF[mi], WH[ni], acc[mi][ni], 0, 0, 0);
                        acc[mi][ni] = __builtin_amdgcn_mfma_f32_16x16x32_f16(AF[mi], WL[ni], acc[mi][ni], 0, 0, 0);
                    }
            }
        }
        __syncthreads();  // waves done reading buf; staged c+1 drained
    }

    float sm = __expf(fminf(smul[h], 4.6051702f));  // ln(100)
#pragma unroll
    for (int mi = 0; mi < 4; mi++) {
#pragma unroll
        for (int r = 0; r < 4; r++) {
            long rowg = m0 + mi * 16 + quad * 4 + r;
            float v[4];
            float ss = 0.f;
#pragma unroll
            for (int ni = 0; ni < 4; ni++) {
                v[ni] = acc[mi][ni][r] + qb[h * 64 + ni * 16 + lr];
                ss += v[ni] * v[ni];
            }
            ss += __shfl_xor(ss, 1, 64); ss += __shfl_xor(ss, 2, 64);
            ss += __shfl_xor(ss, 4, 64); ss += __shfl_xor(ss, 8, 64);
            float inv = sm / fmaxf(sqrtf(ss), 1e-12f);
            int l = (int)(rowg % L);
            f16* orow = qout + rowg * 1024 + h * 64;
#pragma unroll
            for (int ni = 0; ni < 4; ni++) {
                float u = v[ni] * inv;
                int d = ni * 16 + lr;
                int j = d >> 1;
                float c = fc[(l * 32 + j) * 2];
                float s = fc[(l * 32 + j) * 2 + 1];
                float pr = __shfl_xor(u, 1, 64);
                float o = (lane & 1) ? (pr * s + u * c) : (u * c - pr * s);
                orow[d] = (f16)o;
            }
        }
    }
}

// ---------------------------------------------------------------------------
// MFMA attention (round-9 best, plain indexing). Block = 4 indep waves.
// ---------------------------------------------------------------------------
__global__ __launch_bounds__(256, 3) void attn(const f16* q,
                                               const f16* __restrict__ khp,
                                               const f16* __restrict__ klp,
                                               const f16* __restrict__ vhp,
                                               const f16* __restrict__ vlp,
                                               const float* __restrict__ abias,
                                               f16* aout) {
    const int L = 1704;
    __shared__ __align__(16) f16 ps[4][16][152];  // 19.5 KB, per-wave regions
    int tid = threadIdx.x;
    int lane = tid & 63, wv = tid >> 6;
    int lr = lane & 15, quad = lane >> 4;
    int ltile = blockIdx.x % 27;
    int bh = blockIdx.x / 27;  // b*16+h
    int h = bh & 15, b = bh >> 4;
    int l0 = ltile * 64;
    int rows = min(64, L - l0);  // 64 or 40 (tail)

    int rA = wv * 16 + lr;
    int rAc = min(rA, rows - 1);
    const f16* qrow = q + ((long)(b * L + l0 + rAc)) * 1024 + h * 64;
    f16x8 qa0 = *reinterpret_cast<const f16x8*>(qrow + quad * 8);
    f16x8 qa1 = *reinterpret_cast<const f16x8*>(qrow + 32 + quad * 8);

    const f16* khb = khp + (long)bh * (144 * 64);
    const f16* klb = klp + (long)bh * (144 * 64);

    f32x4 acc[9] = {};
#pragma unroll
    for (int t = 0; t < 9; t++) {
        const f16* k0 = khb + (t * 16 + lr) * 64 + quad * 8;
        const f16* k1 = klb + (t * 16 + lr) * 64 + quad * 8;
        f16x8 bh0 = *reinterpret_cast<const f16x8*>(k0);
        f16x8 bh1 = *reinterpret_cast<const f16x8*>(k0 + 32);
        f16x8 bl0 = *reinterpret_cast<const f16x8*>(k1);
        f16x8 bl1 = *reinterpret_cast<const f16x8*>(k1 + 32);
        __builtin_amdgcn_s_setprio(1);
        acc[t] = __builtin_amdgcn_mfma_f32_16x16x32_f16(qa0, bh0, acc[t], 0, 0, 0);
        acc[t] = __builtin_amdgcn_mfma_f32_16x16x32_f16(qa1, bh1, acc[t], 0, 0, 0);
        acc[t] = __builtin_amdgcn_mfma_f32_16x16x32_f16(qa0, bl0, acc[t], 0, 0, 0);
        acc[t] = __builtin_amdgcn_mfma_f32_16x16x32_f16(qa1, bl1, acc[t], 0, 0, 0);
        __builtin_amdgcn_s_setprio(0);
    }

    int rC = wv * 16 + quad * 4;
#pragma unroll
    for (int r = 0; r < 4; r++) {
        long lrow = (long)(l0 + min(rC + r, rows - 1)) * 144;
#pragma unroll
        for (int t = 0; t < 9; t++) acc[t][r] += abias[lrow + t * 16 + lr];
    }

#pragma unroll
    for (int r = 0; r < 4; r++) {
        float mx = acc[0][r];
#pragma unroll
        for (int t = 1; t < 9; t++) mx = fmaxf(mx, acc[t][r]);
        mx = fmaxf(mx, __shfl_xor(mx, 1, 64));
        mx = fmaxf(mx, __shfl_xor(mx, 2, 64));
        mx = fmaxf(mx, __shfl_xor(mx, 4, 64));
        mx = fmaxf(mx, __shfl_xor(mx, 8, 64));
        float s = 0.f;
#pragma unroll
        for (int t = 0; t < 9; t++) {
            float e = __expf(acc[t][r] - mx);
            acc[t][r] = e;
            s += e;
        }
        s += __shfl_xor(s, 1, 64);
        s += __shfl_xor(s, 2, 64);
        s += __shfl_xor(s, 4, 64);
        s += __shfl_xor(s, 8, 64);
        float inv = 1.0f / s;
#pragma unroll
        for (int t = 0; t < 9; t++)
            ps[wv][quad * 4 + r][t * 16 + lr] = (f16)(acc[t][r] * inv);
    }

    const f16* vhb = vhp + (long)bh * (64 * 144);
    const f16* vlb = vlp + (long)bh * (64 * 144);
    f32x4 oacc[4] = {};
#pragma unroll
    for (int ks = 0; ks < 5; ks++) {
        f16x8 pa = {0, 0, 0, 0, 0, 0, 0, 0};
        if (ks < 4 || quad < 2)
            pa = *reinterpret_cast<const f16x8*>(&ps[wv][lr][ks * 32 + quad * 8]);
#pragma unroll
        for (int n = 0; n < 4; n++) {
            f16x8 vh8 = {0, 0, 0, 0, 0, 0, 0, 0};
            f16x8 vl8 = {0, 0, 0, 0, 0, 0, 0, 0};
            if (ks < 4 || quad < 2) {
                const f16* vr  = vhb + (n * 16 + lr) * 144 + ks * 32 + quad * 8;
                const f16* vr2 = vlb + (n * 16 + lr) * 144 + ks * 32 + quad * 8;
                vh8 = *reinterpret_cast<const f16x8*>(vr);
                vl8 = *reinterpret_cast<const f16x8*>(vr2);
            }
            __builtin_amdgcn_s_setprio(1);
            oacc[n] = __builtin_amdgcn_mfma_f32_16x16x32_f16(pa, vh8, oacc[n], 0, 0, 0);
            oacc[n] = __builtin_amdgcn_mfma_f32_16x16x32_f16(pa, vl8, oacc[n], 0, 0, 0);
            __builtin_amdgcn_s_setprio(0);
        }
    }

    long ob = (long)(b * L + l0);
#pragma unroll
    for (int r = 0; r < 4; r++) {
        int rw = rC + r;
        if (rw < rows) {
            f16* ao = aout + (ob + rw) * 1024 + h * 64;
#pragma unroll
            for (int n = 0; n < 4; n++) ao[n * 16 + lr] = (f16)oacc[n][r];
        }
    }
}

// ---------------------------------------------------------------------------
// Final projection (round-9 best: BK=128, 64-row m-tiles, 852 blocks,
// remap852). A f16 staged (dbl-buffered 32 KB, swizzled), W f16 direct.
// ---------------------------------------------------------------------------
__global__ __launch_bounds__(256) void gemm_proj(const f16* __restrict__ A,
                                                 const f16* __restrict__ Wh,
                                                 const float* __restrict__ bias,
                                                 float* __restrict__ out) {
    const int K = 1024;
    __shared__ f16 as[2][2][64][64];  // [buf][khalf][row][k] = 32 KB (swizzled)
    int tid = threadIdx.x;
    int lane = tid & 63, wv = tid >> 6;
    int mt, cg;
    remap852(blockIdx.x, mt, cg);
    int lr = lane & 15, quad = lane >> 4;
    long m0 = (long)mt * 64;
    long n0 = (long)cg * 256 + wv * 64;

    int r0 = tid >> 3, c0 = tid & 7;
    int s1i = tid + 256;
    int r1 = s1i >> 3, c1 = s1i & 7;
    const f16* srca0 = A + (m0 + r0) * K + ((c0 ^ (r0 & 7)) * 8);
    const f16* srca1 = A + (m0 + r1) * K + ((c1 ^ (r1 & 7)) * 8);
    f16* da[2][2][2];
#pragma unroll
    for (int b = 0; b < 2; b++)
#pragma unroll
        for (int hh = 0; hh < 2; hh++) {
            da[b][hh][0] = &as[b][hh][r0][c0 * 8];
            da[b][hh][1] = &as[b][hh][r1][c1 * 8];
        }

    const f16x8* wrow[4];
#pragma unroll
    for (int i = 0; i < 4; i++)
        wrow[i] = reinterpret_cast<const f16x8*>(Wh + (n0 + i * 16 + lr) * K) + quad;

    int sp0 = ((0 + quad) ^ (lr & 7)) * 8;
    int sp1 = ((4 + quad) ^ (lr & 7)) * 8;

    f32x4 acc[4][4] = {};

    async_cp16(da[0][0][0], srca0);      async_cp16(da[0][0][1], srca1);
    async_cp16(da[0][1][0], srca0 + 64); async_cp16(da[0][1][1], srca1 + 64);
    __syncthreads();

    for (int c = 0; c < 8; c++) {
        if (c < 7) {
            int nb = (c + 1) & 1;
            int off = (c + 1) * 128;
            async_cp16(da[nb][0][0], srca0 + off);      async_cp16(da[nb][0][1], srca1 + off);
            async_cp16(da[nb][1][0], srca0 + off + 64); async_cp16(da[nb][1][1], srca1 + off + 64);
        }
        int buf = c & 1;
#pragma unroll
        for (int hh = 0; hh < 2; hh++) {
#pragma unroll
            for (int s = 0; s < 2; s++) {
                int o = (c * 2 + hh) * 8 + s * 4;
                int sp = s ? sp1 : sp0;
                f16x8 af[4], wf[4];
#pragma unroll
                for (int i = 0; i < 4; i++) wf[i] = wrow[i][o];
#pragma unroll
                for (int i = 0; i < 4; i++)
                    af[i] = *reinterpret_cast<const f16x8*>(&as[buf][hh][i * 16 + lr][sp]);
#pragma unroll
                for (int mi = 0; mi < 4; mi++)
#pragma unroll
                    for (int ni = 0; ni < 4; ni++)
                        acc[mi][ni] = __builtin_amdgcn_mfma_f32_16x16x32_f16(af[mi], wf[ni], acc[mi][ni], 0, 0, 0);
            }
        }
        __syncthreads();
    }

#pragma unroll
    for (int ni = 0; ni < 4; ni++) {
        int col = (int)n0 + ni * 16 + lr;
        float b = bias[col];
#pragma unroll
        for (int mi = 0; mi < 4; mi++) {
            long row = m0 + mi * 16 + quad * 4;
#pragma unroll
            for (int r = 0; r < 4; r++)
                out[(row + r) * 1024 + col] = acc[mi][ni][r] + b;
        }
    }
}

extern "C" void kernel_launch(void* const* d_in, const int* in_sizes, int n_in,
                              void* d_out, int out_size, void* d_ws, size_t ws_size,
                              hipStream_t stream) {
    const float* x     = (const float*)d_in[0];
    const float* y     = (const float*)d_in[1];
    const float* fc    = (const float*)d_in[2];
    const float* abias = (const float*)d_in[3];
    const float* Wq    = (const float*)d_in[4];
    const float* qb    = (const float*)d_in[5];
    const float* Wkv   = (const float*)d_in[6];
    const float* vb    = (const float*)d_in[7];
    const float* Wp    = (const float*)d_in[8];
    const float* bp    = (const float*)d_in[9];
    const float* smul  = (const float*)d_in[10];

    const long XN  = 13959168L;  // 8*1704*1024
    const long WN  = 1048576L;   // 1024*1024
    const long YN  = 1179648L;   // 8*144*1024
    const long WKN = 2097152L;   // 2048*1024
    const long KVN = 1179648L;   // 128*144*64 (= 128*64*144)

    // d_ws layout (33.9 MB): qbuf fp16 | Wq hi f16 | Wq lo f16 | Wp fp16
    f16* qbuf  = (f16*)d_ws;
    f16* wq_hi = qbuf + XN;
    f16* wq_lo = wq_hi + WN;
    f16* wp_h  = wq_lo + WN;

    // d_out (55.8 MB), 50.4 MB used:
    //   x f16 (27.9) | y bf16 hi/lo (4.7) | Wkv bf16 hi/lo (8.4) | K/V planes (9.4)
    // K/V planes AFTER the Wkv planes because the fused qkv kernel writes
    // them while q-blocks still read x_f (no aliasing). All dead before
    // gemm_proj overwrites d_out with the fp32 output.
    f16* x_f   = (f16*)d_out;
    u16* y_hi  = (u16*)(x_f + XN);
    u16* y_lo  = y_hi + YN;
    u16* wk_hi = y_lo + YN;
    u16* wk_lo = wk_hi + WKN;
    f16* kh_p  = (f16*)(wk_lo + WKN);
    f16* kl_p  = kh_p + KVN;
    f16* vth_p = kl_p + KVN;
    f16* vtl_p = vth_p + KVN;

    int nx4  = (int)(XN / 4);
    int nw4  = (int)(WN / 4);
    int ny4  = (int)(YN / 4);
    int nwk4 = (int)(WKN / 4);
    int prep_blocks = (nx4 + 2 * nw4 + ny4 + nwk4 + 255) / 256;

    prep<<<dim3(prep_blocks), dim3(256), 0, stream>>>(
        x, Wq, Wp, y, Wkv, x_f, wq_hi, wq_lo, wp_h,
        y_hi, y_lo, wk_hi, wk_lo, nx4, nw4, ny4, nwk4);
    qkv<<<dim3(288 + 852), dim3(256), 0, stream>>>(
        x_f, wq_hi, wq_lo, qb, fc, smul, qbuf,
        y_hi, y_lo, wk_hi, wk_lo, vb, kh_p, kl_p, vth_p, vtl_p);
    attn<<<dim3(3456), dim3(256), 0, stream>>>(qbuf, kh_p, kl_p, vth_p, vtl_p, abias, (f16*)qbuf);
    gemm_proj<<<dim3(852), dim3(256), 0, stream>>>((const f16*)qbuf, wp_h, bp, (float*)d_out);
}